// Round 1
// baseline (1142.296 us; speedup 1.0000x reference)
//
#include <hip/hip_runtime.h>
#include <hip/hip_bf16.h>

#define NUM_G 4096
#define N_NODE 32
#define N_REAL 31
#define E_G 93
#define C_IN 64
#define C_E 64
#define NH 4
#define HD 64
#define OUT2_OFF ((size_t)NUM_G * N_NODE * HD)   // 8388608

__device__ __forceinline__ float lrelu(float v) { return v > 0.f ? v : 0.01f * v; }

// local src node of edge e in the fixed per-graph topology
__device__ __forceinline__ int src_of(int e) {
    if (e < 62) { int i = e >> 1; return (e & 1) ? ((i + 1) % 31) : i; }
    return e - 62;
}

// ---------------- Kernel 1: GAT attention + aggregation (one block per graph) ----
__global__ __launch_bounds__(256, 1) void gat_part1(
    const float* __restrict__ x, const float* __restrict__ einf,
    const float* __restrict__ W, const float* __restrict__ att,
    const float* __restrict__ bias, float* __restrict__ out)
{
    __shared__ float xl[N_NODE * C_IN];        // 2048 f  (8 KB)
    __shared__ float el[E_G * C_E];            // 5952 f  (23.25 KB)
    __shared__ __hip_bfloat16 hl[E_G * 128];   // per-pass h, bf16 (23.25 KB)
    __shared__ float al[E_G * 2];              // per-pass alpha -> softmax weights

    const int t = threadIdx.x;
    const int g = blockIdx.x;

    // cooperative staging (coalesced float4)
    {
        const float4* xg4 = (const float4*)(x + (size_t)g * N_NODE * C_IN);
        const float4* eg4 = (const float4*)(einf + (size_t)g * E_G * C_E);
        float4* xl4 = (float4*)xl;
        float4* el4 = (float4*)el;
        for (int i = t; i < N_NODE * C_IN / 4; i += 256) xl4[i] = xg4[i];
        for (int i = t; i < E_G * C_E / 4; i += 256) el4[i] = eg4[i];
    }
    __syncthreads();

    const int c    = t & 127;   // pass-local output column
    const int par  = t >> 7;    // edge parity handled by this thread
    const int hp   = c >> 6;    // head-in-pair (0/1)
    const int lane = t & 63;

    float out_acc[8];
    #pragma unroll
    for (int i = 0; i < 8; ++i) out_acc[i] = 0.f;

    for (int p = 0; p < 2; ++p) {
        // my W column (128 deep) in registers; coalesced loads
        float wcol[128];
        #pragma unroll
        for (int k = 0; k < 128; ++k) wcol[k] = W[k * 256 + p * 128 + c];
        const float attv = att[p * 128 + c];

        // matmul: h[e][c] = [x[src]; einf[e]] . wcol  (LDS reads are wave-broadcast)
        for (int e = par; e < E_G; e += 2) {
            const int s = src_of(e);
            const float4* a4 = (const float4*)(xl + s * C_IN);
            const float4* b4 = (const float4*)(el + e * C_E);
            float ac0 = 0.f, ac1 = 0.f, ac2 = 0.f, ac3 = 0.f;
            #pragma unroll
            for (int kk = 0; kk < 16; ++kk) {
                float4 v = a4[kk];
                ac0 += v.x * wcol[kk * 4 + 0];
                ac1 += v.y * wcol[kk * 4 + 1];
                ac2 += v.z * wcol[kk * 4 + 2];
                ac3 += v.w * wcol[kk * 4 + 3];
            }
            #pragma unroll
            for (int kk = 0; kk < 16; ++kk) {
                float4 v = b4[kk];
                ac0 += v.x * wcol[64 + kk * 4 + 0];
                ac1 += v.y * wcol[64 + kk * 4 + 1];
                ac2 += v.z * wcol[64 + kk * 4 + 2];
                ac3 += v.w * wcol[64 + kk * 4 + 3];
            }
            const float acc = (ac0 + ac1) + (ac2 + ac3);
            hl[e * 128 + c] = __float2bfloat16(acc);
            // alpha[e][head] = sum over this wave's 64 columns of h*att
            float r = acc * attv;
            #pragma unroll
            for (int off = 32; off > 0; off >>= 1) r += __shfl_down(r, off, 64);
            if (lane == 0) al[e * 2 + hp] = lrelu(r);
        }
        __syncthreads();

        // softmax per (node, head-in-pair); segments are static: 2 edges (real), 31 (virtual)
        if (t < 64) {
            const int j = t >> 1, q = t & 1;
            if (j < N_REAL) {
                const int e1 = 2 * ((j + 30) % 31), e2 = 2 * j + 1;
                const float a1 = al[e1 * 2 + q], a2 = al[e2 * 2 + q];
                const float m  = fmaxf(a1, a2);
                const float x1 = expf(a1 - m), x2 = expf(a2 - m);
                const float inv = 1.f / (x1 + x2 + 1e-16f);
                al[e1 * 2 + q] = x1 * inv;
                al[e2 * 2 + q] = x2 * inv;
            } else {
                float m = -1e30f;
                for (int i = 0; i < 31; ++i) m = fmaxf(m, al[(62 + i) * 2 + q]);
                float sden = 1e-16f;
                for (int i = 0; i < 31; ++i) sden += expf(al[(62 + i) * 2 + q] - m);
                const float inv = 1.f / sden;
                for (int i = 0; i < 31; ++i)
                    al[(62 + i) * 2 + q] = expf(al[(62 + i) * 2 + q] - m) * inv;
            }
        }
        __syncthreads();

        // aggregation: out[n][d] += sum over in-edges, both heads of this pass
        #pragma unroll
        for (int i = 0; i < 8; ++i) {
            const int n = (t >> 6) + i * 4;
            const int d = t & 63;
            float acc = 0.f;
            if (n < N_REAL) {
                const int e1 = 2 * ((n + 30) % 31), e2 = 2 * n + 1;
                acc += al[e1 * 2 + 0] * __bfloat162float(hl[e1 * 128 + d]);
                acc += al[e1 * 2 + 1] * __bfloat162float(hl[e1 * 128 + 64 + d]);
                acc += al[e2 * 2 + 0] * __bfloat162float(hl[e2 * 128 + d]);
                acc += al[e2 * 2 + 1] * __bfloat162float(hl[e2 * 128 + 64 + d]);
            } else {
                for (int q = 0; q < 31; ++q) {
                    const int e = 62 + q;
                    acc += al[e * 2 + 0] * __bfloat162float(hl[e * 128 + d]);
                    acc += al[e * 2 + 1] * __bfloat162float(hl[e * 128 + 64 + d]);
                }
            }
            out_acc[i] += acc;
        }
        __syncthreads();   // protect hl/al before next pass overwrites
    }

    const int d = t & 63;
    const float bv = bias[d];
    #pragma unroll
    for (int i = 0; i < 8; ++i) {
        const int n = (t >> 6) + i * 4;
        out[((size_t)g * N_NODE + n) * HD + d] = 0.25f * out_acc[i] + bv;
    }
}

// ---------------- Kernel 2: edge-feature update (one block per graph) -----------
__global__ __launch_bounds__(256, 1) void edge_part2(
    const float* __restrict__ einf, const float* __restrict__ Wec,
    const float* __restrict__ bec, float* __restrict__ out2)
{
    __shared__ float el[E_G * C_E];   // 5952 f
    __shared__ float ul[63 * 64];     // rows 0..30 temp, 31..61 eisum, 62 esum(virtual)
    __shared__ float wl[64 * 64];     // W_ec

    const int t = threadIdx.x;
    const int g = blockIdx.x;

    {
        const float4* eg4 = (const float4*)(einf + (size_t)g * E_G * C_E);
        float4* el4 = (float4*)el;
        for (int i = t; i < E_G * C_E / 4; i += 256) el4[i] = eg4[i];
        const float4* wg4 = (const float4*)Wec;
        float4* wl4 = (float4*)wl;
        for (int i = t; i < 64 * 64 / 4; i += 256) wl4[i] = wg4[i];
    }
    __syncthreads();

    // eisum for real nodes (each has exactly 2 ring in-edges)
    for (int idx = t; idx < 31 * 64; idx += 256) {
        const int j = idx >> 6, cc = idx & 63;
        const int e1 = 2 * ((j + 30) % 31), e2 = 2 * j + 1;
        ul[(31 + j) * 64 + cc] = el[e1 * 64 + cc] + el[e2 * 64 + cc];
    }
    // sum over the 31 virtual-node in-edges
    if (t < 64) {
        float s = 0.f;
        for (int i = 0; i < 31; ++i) s += el[(62 + i) * 64 + t];
        ul[62 * 64 + t] = s;
    }
    __syncthreads();

    // temp[i] = eisum[i] + eisum[(i+1)%31] - einf[2i]   (norm-1 == 1 by construction)
    for (int idx = t; idx < 31 * 64; idx += 256) {
        const int i = idx >> 6, cc = idx & 63;
        ul[i * 64 + cc] = ul[(31 + i) * 64 + cc] + ul[(31 + (i + 1) % 31) * 64 + cc]
                        - el[(2 * i) * 64 + cc];
    }
    __syncthreads();

    // dedup GEMM: 63 unique rows -> 125 output rows
    const int co = t & 63;
    const float bv = bec[co];
    const size_t base = (size_t)g * 125;
    for (int it = 0; it < 16; ++it) {
        const int ur = (t >> 6) + it * 4;
        if (ur >= 63) break;              // wave-uniform
        float acc = 0.f;
        const float4* u4 = (const float4*)(ul + ur * 64);
        #pragma unroll
        for (int cc = 0; cc < 16; ++cc) {
            float4 v = u4[cc];
            acc += v.x * wl[(cc * 4 + 0) * 64 + co];
            acc += v.y * wl[(cc * 4 + 1) * 64 + co];
            acc += v.z * wl[(cc * 4 + 2) * 64 + co];
            acc += v.w * wl[(cc * 4 + 3) * 64 + co];
        }
        if (ur < 31) {                     // temp rows -> output rows 2i, 2i+1
            const float v = lrelu(acc + bv);
            out2[(base + 2 * ur) * 64 + co]     = v;
            out2[(base + 2 * ur + 1) * 64 + co] = v;
        } else if (ur < 62) {              // emean real -> rows 62+j and 94+j
            const int j = ur - 31;
            const float v = lrelu(0.5f * acc + bv);
            out2[(base + 62 + j) * 64 + co] = v;
            out2[(base + 94 + j) * 64 + co] = v;
        } else {                           // emean virtual -> row 93
            const float v = lrelu(acc * (1.0f / 31.0f) + bv);
            out2[(base + 93) * 64 + co] = v;
        }
    }
}

extern "C" void kernel_launch(void* const* d_in, const int* in_sizes, int n_in,
                              void* d_out, int out_size, void* d_ws, size_t ws_size,
                              hipStream_t stream) {
    const float* x    = (const float*)d_in[0];
    const float* einf = (const float*)d_in[2];
    const float* W    = (const float*)d_in[5];
    const float* att  = (const float*)d_in[6];
    const float* bias = (const float*)d_in[7];
    const float* Wec  = (const float*)d_in[8];
    const float* bec  = (const float*)d_in[9];
    float* out  = (float*)d_out;
    float* out2 = out + OUT2_OFF;

    gat_part1<<<NUM_G, 256, 0, stream>>>(x, einf, W, att, bias, out);
    edge_part2<<<NUM_G, 256, 0, stream>>>(einf, Wec, bec, out2);
}

// Round 2
// 382.399 us; speedup vs baseline: 2.9872x; 2.9872x over previous
//
#include <hip/hip_runtime.h>
#include <hip/hip_bf16.h>

#define NUM_G 4096
#define N_REAL 31
#define E_G 93
#define XLS 68                 // padded LDS row stride (floats) for x/einf
#define OUT2_OFF ((size_t)NUM_G * 32 * 64)   // 8388608

typedef short  short8  __attribute__((ext_vector_type(8)));
typedef float  floatx4 __attribute__((ext_vector_type(4)));

__device__ __forceinline__ float lrelu(float v) { return v > 0.f ? v : 0.01f * v; }

__device__ __forceinline__ int src_of(int e) {
    if (e < 62) { int i = e >> 1; return (e & 1) ? ((i + 1) % 31) : i; }
    return e - 62;
}

__device__ __forceinline__ unsigned short f2bf(float f) {
    __hip_bfloat16 h = __float2bfloat16(f);
    unsigned short u; __builtin_memcpy(&u, &h, 2); return u;
}

// ---------- setup: vt = W^T-slices . att (fp32), BT = B' transposed (bf16),
// ---------- BT2 = W_ec transposed (bf16). Recomputed every launch (ws re-poisoned).
__global__ void setup_prep(const float* __restrict__ W, const float* __restrict__ att,
                           const float* __restrict__ Wec,
                           float* __restrict__ vt, __hip_bfloat16* __restrict__ BT,
                           __hip_bfloat16* __restrict__ BT2)
{
    const int t = threadIdx.x, b = blockIdx.x;   // grid 8 x 256
    if (b == 0) {
        for (int i = t; i < 512; i += 256) {     // vt[k*4+h] = sum_d W[k][h*64+d]*att[h][d]
            const int k = i >> 2, h = i & 3;
            float acc = 0.f;
            for (int d = 0; d < 64; ++d) acc += W[k * 256 + h * 64 + d] * att[h * 64 + d];
            vt[i] = acc;
        }
    }
    // BT[d][h*128+k] = W[k][h*64+d]   (64 x 512 bf16)
    for (int i = b * 4096 + t; i < (b + 1) * 4096; i += 256) {
        const int d = i >> 9, kk = i & 511;
        const int h = kk >> 7, k = kk & 127;
        BT[i] = __float2bfloat16(W[k * 256 + h * 64 + d]);
    }
    // BT2[d][k] = Wec[k][d]           (64 x 64 bf16)
    for (int i = b * 512 + t; i < b * 512 + 512; i += 256) {
        const int d = i >> 6, k = i & 63;
        BT2[i] = __float2bfloat16(Wec[k * 64 + d]);
    }
}

// ---------- fused: alpha -> softmax -> P -> MFMA out0 -> part2 (eisum/temp) -> MFMA out2
__global__ __launch_bounds__(256, 2) void fused_main(
    const float* __restrict__ x, const float* __restrict__ einf,
    const float* __restrict__ bias, const float* __restrict__ bec,
    const float* __restrict__ vt, const __hip_bfloat16* __restrict__ BT,
    const __hip_bfloat16* __restrict__ BT2,
    float* __restrict__ out, float* __restrict__ out2)
{
    __shared__ __align__(16) float xl[32 * XLS];     // 8704 B
    __shared__ __align__(16) float el[E_G * XLS];    // 25296 B
    __shared__ float vl[512];                        // 2048 B
    __shared__ float al4[96 * 4];                    // 1536 B
    __shared__ __align__(16) unsigned char U[33280]; // union region
    unsigned short* Ap = (unsigned short*)U;                 // 32 x 520 bf16 (A' for out0 GEMM)
    float*          ul = (float*)U;                          // 63 x 64 f32 (eisum/esum)
    unsigned short* A2 = (unsigned short*)(U + 16384);       // 64 x 72 bf16 (A for out2 GEMM)

    const int t = threadIdx.x;
    const int g = blockIdx.x;
    const int lane = t & 63;
    const int w = t >> 6;          // wave id == N-tile (16 output cols)
    const int m16 = lane & 15, q = lane >> 4;

    // ---- stage x, einf (coalesced float4, padded rows), vt ----
    {
        const float4* xg4 = (const float4*)(x + (size_t)g * 2048);
        const float4* eg4 = (const float4*)(einf + (size_t)g * 5952);
        for (int i = t; i < 32 * 16; i += 256)
            ((float4*)(xl + (i >> 4) * XLS))[i & 15] = xg4[i];
        for (int i = t; i < E_G * 16; i += 256)
            ((float4*)(el + (i >> 4) * XLS))[i & 15] = eg4[i];
        vl[t] = vt[t]; vl[t + 256] = vt[t + 256];
    }
    __syncthreads();

    // ---- alpha[e][h] = lrelu( x[src].vt_x_h + einf[e].vt_e_h )  (fp32) ----
    for (int i = t; i < E_G * 4; i += 256) {
        const int e = i >> 2, h = i & 3;
        const int s = src_of(e);
        float acc = 0.f;
        for (int k = 0; k < 64; ++k)
            acc += xl[s * XLS + k] * vl[k * 4 + h] + el[e * XLS + k] * vl[(64 + k) * 4 + h];
        al4[e * 4 + h] = lrelu(acc);
    }
    __syncthreads();

    // ---- softmax per (dst node, head); static segments: 2 (real) / 31 (virtual) ----
    if (t < 128) {
        const int n = t >> 2, h = t & 3;
        if (n < N_REAL) {
            const int e1 = 2 * ((n + 30) % 31), e2 = 2 * n + 1;
            const float a1 = al4[e1 * 4 + h], a2 = al4[e2 * 4 + h];
            const float m = fmaxf(a1, a2);
            const float x1 = __expf(a1 - m), x2 = __expf(a2 - m);
            const float inv = 1.f / (x1 + x2 + 1e-16f);
            al4[e1 * 4 + h] = x1 * inv;
            al4[e2 * 4 + h] = x2 * inv;
        } else {
            float m = -1e30f;
            for (int i = 0; i < 31; ++i) m = fmaxf(m, al4[(62 + i) * 4 + h]);
            float sden = 1e-16f;
            for (int i = 0; i < 31; ++i) sden += __expf(al4[(62 + i) * 4 + h] - m);
            const float inv = 1.f / sden;
            for (int i = 0; i < 31; ++i)
                al4[(62 + i) * 4 + h] = __expf(al4[(62 + i) * 4 + h] - m) * inv;
        }
    }
    __syncthreads();

    // ---- P formation: A'[n][h*128 + half*64 + k] (bf16), weighted sums of x / einf ----
    if (t < 248) {  // real nodes: (n, h, half)
        const int n = t >> 3, h = (t >> 1) & 3, half = t & 1;
        const int e1 = 2 * ((n + 30) % 31), e2 = 2 * n + 1;
        const int s1 = (n + 30) % 31, s2 = (n + 1) % 31;
        const float a1 = al4[e1 * 4 + h], a2 = al4[e2 * 4 + h];
        const float* r1 = half ? (el + e1 * XLS) : (xl + s1 * XLS);
        const float* r2 = half ? (el + e2 * XLS) : (xl + s2 * XLS);
        unsigned short* dst = Ap + n * 520 + h * 128 + half * 64;
        for (int k = 0; k < 64; ++k)
            dst[k] = f2bf(a1 * r1[k] + a2 * r2[k]);
    }
    for (int u = t; u < 512; u += 256) {  // virtual node row 31
        const int h = u >> 7, kp = u & 127;
        const int half = kp >> 6, k = kp & 63;
        float acc = 0.f;
        for (int i = 0; i < 31; ++i) {
            const float a = al4[(62 + i) * 4 + h];
            acc += a * (half ? el[(62 + i) * XLS + k] : xl[i * XLS + k]);
        }
        Ap[31 * 520 + h * 128 + kp] = f2bf(acc);
    }
    __syncthreads();

    // ---- MFMA GEMM 1: out0 = 0.25 * A'(32x512) @ B'(512x64) + bias ----
    {
        floatx4 acc0 = {0.f, 0.f, 0.f, 0.f}, acc1 = {0.f, 0.f, 0.f, 0.f};
        const unsigned short* bt = (const unsigned short*)BT;
        #pragma unroll
        for (int kk = 0; kk < 16; ++kk) {
            short8 b  = *(const short8*)(bt + (w * 16 + m16) * 512 + kk * 32 + q * 8);
            short8 a0 = *(const short8*)(Ap + m16 * 520 + kk * 32 + q * 8);
            short8 a1 = *(const short8*)(Ap + (16 + m16) * 520 + kk * 32 + q * 8);
            acc0 = __builtin_amdgcn_mfma_f32_16x16x32_bf16(a0, b, acc0, 0, 0, 0);
            acc1 = __builtin_amdgcn_mfma_f32_16x16x32_bf16(a1, b, acc1, 0, 0, 0);
        }
        const float bv = bias[w * 16 + m16];
        float* og = out + (size_t)g * 2048;
        #pragma unroll
        for (int r = 0; r < 4; ++r) {
            og[(q * 4 + r) * 64 + w * 16 + m16]      = 0.25f * acc0[r] + bv;
            og[(16 + q * 4 + r) * 64 + w * 16 + m16] = 0.25f * acc1[r] + bv;
        }
    }
    __syncthreads();   // A' dead; reuse U for part 2

    // ---- part 2: eisum (real, 2 in-edges) and esum (virtual) in fp32 ----
    for (int idx = t; idx < 31 * 64; idx += 256) {
        const int j = idx >> 6, cc = idx & 63;
        const int e1 = 2 * ((j + 30) % 31), e2 = 2 * j + 1;
        ul[(31 + j) * 64 + cc] = el[e1 * XLS + cc] + el[e2 * XLS + cc];
    }
    if (t < 64) {
        float s = 0.f;
        for (int i = 0; i < 31; ++i) s += el[(62 + i) * XLS + t];
        ul[62 * 64 + t] = s;
    }
    __syncthreads();

    // ---- A2 rows (bf16): 0..30 temp, 31..61 emean_real, 62 emean_virt, 63 zero ----
    for (int idx = t; idx < 64 * 64; idx += 256) {
        const int r = idx >> 6, k = idx & 63;
        float v;
        if (r < 31)       v = ul[(31 + r) * 64 + k] + ul[(31 + (r + 1) % 31) * 64 + k]
                              - el[(2 * r) * XLS + k];
        else if (r < 62)  v = 0.5f * ul[r * 64 + k];
        else if (r == 62) v = (1.0f / 31.0f) * ul[62 * 64 + k];
        else              v = 0.f;
        A2[r * 72 + k] = f2bf(v);
    }
    __syncthreads();

    // ---- MFMA GEMM 2: out2 rows = lrelu(A2(64x64) @ W_ec + b_ec), dedup stores ----
    {
        floatx4 z = {0.f, 0.f, 0.f, 0.f};
        floatx4 acc2[4]; acc2[0] = z; acc2[1] = z; acc2[2] = z; acc2[3] = z;
        const unsigned short* bt2 = (const unsigned short*)BT2;
        #pragma unroll
        for (int kk = 0; kk < 2; ++kk) {
            short8 b = *(const short8*)(bt2 + (w * 16 + m16) * 64 + kk * 32 + q * 8);
            #pragma unroll
            for (int mt = 0; mt < 4; ++mt) {
                short8 a = *(const short8*)(A2 + (mt * 16 + m16) * 72 + kk * 32 + q * 8);
                acc2[mt] = __builtin_amdgcn_mfma_f32_16x16x32_bf16(a, b, acc2[mt], 0, 0, 0);
            }
        }
        const int co = w * 16 + m16;
        const float bv2 = bec[co];
        float* o2 = out2 + (size_t)g * 8000;   // 125 * 64
        #pragma unroll
        for (int mt = 0; mt < 4; ++mt) {
            #pragma unroll
            for (int r = 0; r < 4; ++r) {
                const int row = mt * 16 + q * 4 + r;
                if (row >= 63) continue;       // row 63 is padding
                const float v = lrelu(acc2[mt][r] + bv2);
                if (row < 31) {                // temp -> rows 2i, 2i+1
                    o2[(2 * row) * 64 + co] = v;
                    o2[(2 * row + 1) * 64 + co] = v;
                } else if (row < 62) {         // emean real -> rows 62+j, 94+j
                    o2[(62 + row - 31) * 64 + co] = v;
                    o2[(94 + row - 31) * 64 + co] = v;
                } else {                       // emean virtual -> row 93
                    o2[93 * 64 + co] = v;
                }
            }
        }
    }
}

extern "C" void kernel_launch(void* const* d_in, const int* in_sizes, int n_in,
                              void* d_out, int out_size, void* d_ws, size_t ws_size,
                              hipStream_t stream) {
    const float* x    = (const float*)d_in[0];
    const float* einf = (const float*)d_in[2];
    const float* W    = (const float*)d_in[5];
    const float* att  = (const float*)d_in[6];
    const float* bias = (const float*)d_in[7];
    const float* Wec  = (const float*)d_in[8];
    const float* bec  = (const float*)d_in[9];
    float* out  = (float*)d_out;
    float* out2 = out + OUT2_OFF;

    float* vt            = (float*)d_ws;                              // 512 f32
    __hip_bfloat16* BT   = (__hip_bfloat16*)((char*)d_ws + 2048);     // 64x512 bf16
    __hip_bfloat16* BT2  = (__hip_bfloat16*)((char*)d_ws + 2048 + 65536); // 64x64 bf16

    setup_prep<<<8, 256, 0, stream>>>(W, att, Wec, vt, BT, BT2);
    fused_main<<<NUM_G, 256, 0, stream>>>(x, einf, bias, bec, vt, BT, BT2, out, out2);
}

// Round 3
// 326.041 us; speedup vs baseline: 3.5035x; 1.1729x over previous
//
#include <hip/hip_runtime.h>
#include <hip/hip_fp16.h>

#define NUM_G 4096
#define RS 72                                // LDS row stride in halves (144 B, 16B-aligned)
#define OUT2_OFF ((size_t)NUM_G * 32 * 64)   // 8388608

typedef _Float16 half8  __attribute__((ext_vector_type(8)));
typedef _Float16 half4v __attribute__((ext_vector_type(4)));
typedef _Float16 half2v __attribute__((ext_vector_type(2)));
typedef float    floatx4 __attribute__((ext_vector_type(4)));

__device__ __forceinline__ float lrelu(float v) { return v > 0.f ? v : 0.01f * v; }

// ---------- setup: vp (8x64 f16), BT (64x512 f16), BT2 (64x64 f16) in d_ws ----
__global__ void setup_prep(const float* __restrict__ W, const float* __restrict__ att,
                           const float* __restrict__ Wec,
                           _Float16* __restrict__ vp, _Float16* __restrict__ BT,
                           _Float16* __restrict__ BT2)
{
    const int t = threadIdx.x, b = blockIdx.x;   // grid 8 x 256
    if (b == 0) {
        for (int i = t; i < 512; i += 256) {     // vp[h8*64+k]: h8<4 -> x part, h8>=4 -> e part
            const int h8 = i >> 6, k = i & 63;
            const int h = h8 & 3, ro = (h8 < 4) ? 0 : 64;
            float acc = 0.f;
            for (int d = 0; d < 64; ++d) acc += W[(ro + k) * 256 + h * 64 + d] * att[h * 64 + d];
            vp[i] = (_Float16)acc;
        }
    }
    for (int i = b * 4096 + t; i < (b + 1) * 4096; i += 256) {  // BT[d][h*128+k128]
        const int d = i >> 9, kk = i & 511, h = kk >> 7, k = kk & 127;
        BT[i] = (_Float16)W[k * 256 + h * 64 + d];
    }
    for (int i = b * 512 + t; i < b * 512 + 512; i += 256) {    // BT2[d][k]
        const int d = i >> 6, k = i & 63;
        BT2[i] = (_Float16)Wec[k * 64 + d];
    }
}

// ---------- fused main: one block per graph ----------
__global__ __launch_bounds__(256, 4) void fused_main(
    const float* __restrict__ x, const float* __restrict__ einf,
    const float* __restrict__ bias, const float* __restrict__ bec,
    const _Float16* __restrict__ vp, const _Float16* __restrict__ BT,
    const _Float16* __restrict__ BT2,
    float* __restrict__ out, float* __restrict__ out2)
{
    __shared__ __align__(16) _Float16 R[128 * RS];       // rows 0-31 x, 32-124 einf (18432 B)
    __shared__ __align__(16) unsigned char U[9216];      // union region
    _Float16* vpl  = (_Float16*)U;            // 8 x RS halves   (1152 B)
    float*    sal  = (float*)(U + 1152);      // 128 x 9 f32     (4608 B)
    _Float16* virt = (_Float16*)(U + 5760);   // 512 halves      (1024 B)
    float*    al4  = (float*)(U + 6784);      // 93 x 4 f32      (1488 B)
    _Float16* A2   = (_Float16*)U;            // 64 x RS halves  (9216 B) — after GEMM1

    const int t = threadIdx.x;
    const int g = blockIdx.x;
    const int lane = t & 63;
    const int w = t >> 6;
    const int m16 = lane & 15, q = lane >> 4;

    // ---- stage x, einf -> fp16 LDS rows; vpl ----
    {
        const float4* xg4 = (const float4*)(x + (size_t)g * 2048);
        for (int i = t; i < 512; i += 256) {
            float4 v = xg4[i];
            half4v h4 = {(_Float16)v.x, (_Float16)v.y, (_Float16)v.z, (_Float16)v.w};
            *(half4v*)(R + (i >> 4) * RS + (i & 15) * 4) = h4;
        }
        const float4* eg4 = (const float4*)(einf + (size_t)g * 5952);
        for (int i = t; i < 1488; i += 256) {
            float4 v = eg4[i];
            half4v h4 = {(_Float16)v.x, (_Float16)v.y, (_Float16)v.z, (_Float16)v.w};
            *(half4v*)(R + (32 + (i >> 4)) * RS + (i & 15) * 4) = h4;
        }
        for (int i = t; i < 512; i += 256)
            vpl[(i >> 6) * RS + (i & 63)] = vp[i];
    }
    __syncthreads();

    // ---- alpha pre-activations: S[r][h8] = R[r] . vpl[h8]  (conflict-free) ----
    #pragma unroll
    for (int j = 0; j < 4; ++j) {
        const int combo = t + 256 * j;
        const int r = combo >> 3, h8 = combo & 7;
        const _Float16* rr = R + r * RS;
        const _Float16* vr = vpl + h8 * RS;
        half8 a8 = {0, 0, 0, 0, 0, 0, 0, 0};
        #pragma unroll
        for (int k8 = 0; k8 < 8; ++k8)
            a8 += (*(const half8*)(rr + k8 * 8)) * (*(const half8*)(vr + k8 * 8));
        float s = 0.f;
        #pragma unroll
        for (int jj = 0; jj < 8; ++jj) s += (float)a8[jj];
        sal[r * 9 + h8] = s;
    }
    __syncthreads();

    // ---- softmax per (dst node, head) -> al4[e][h] weights ----
    if (t < 128) {
        const int n = t >> 2, h = t & 3;
        if (n < 31) {
            const int s1 = (n + 30) % 31, s2 = (n + 1) % 31;
            const int e1 = 2 * s1, e2 = 2 * n + 1;
            const float a1 = lrelu(sal[s1 * 9 + h] + sal[(32 + e1) * 9 + 4 + h]);
            const float a2 = lrelu(sal[s2 * 9 + h] + sal[(32 + e2) * 9 + 4 + h]);
            const float m = fmaxf(a1, a2);
            const float x1 = __expf(a1 - m), x2 = __expf(a2 - m);
            const float inv = 1.f / (x1 + x2 + 1e-16f);
            al4[e1 * 4 + h] = x1 * inv;
            al4[e2 * 4 + h] = x2 * inv;
        } else {
            float m = -1e30f;
            for (int i = 0; i < 31; ++i)
                m = fmaxf(m, lrelu(sal[i * 9 + h] + sal[(94 + i) * 9 + 4 + h]));
            float sden = 1e-16f;
            for (int i = 0; i < 31; ++i)
                sden += __expf(lrelu(sal[i * 9 + h] + sal[(94 + i) * 9 + 4 + h]) - m);
            const float inv = 1.f / sden;
            for (int i = 0; i < 31; ++i)
                al4[(62 + i) * 4 + h] =
                    __expf(lrelu(sal[i * 9 + h] + sal[(94 + i) * 9 + 4 + h]) - m) * inv;
        }
    }
    __syncthreads();

    // ---- virtual-node P row (512 cols, fp16) ----
    #pragma unroll
    for (int j = 0; j < 2; ++j) {
        const int c = t + 256 * j;
        const int h = c >> 7, hf = (c >> 6) & 1, k = c & 63;
        float acc = 0.f;
        for (int i = 0; i < 31; ++i)
            acc += al4[(62 + i) * 4 + h] * (float)R[(hf ? 94 + i : i) * RS + k];
        virt[c] = (_Float16)acc;
    }
    __syncthreads();

    // ---- GEMM1: A' fragments formed in registers, MFMA, out0 epilogue ----
    {
        const int n0 = m16, n1 = 16 + m16;
        const int n1c = (n1 < 31) ? n1 : 30;
        const int s1_0 = (n0 + 30) % 31, s2_0 = (n0 + 1) % 31;
        const int e1_0 = 2 * s1_0, e2_0 = 2 * n0 + 1;
        const int s1_1 = (n1c + 30) % 31, s2_1 = (n1c + 1) % 31;
        const int e1_1 = 2 * s1_1, e2_1 = 2 * n1c + 1;
        _Float16 a1_0[4], a2_0[4], a1_1[4], a2_1[4];
        #pragma unroll
        for (int h = 0; h < 4; ++h) {
            a1_0[h] = (_Float16)al4[e1_0 * 4 + h];
            a2_0[h] = (_Float16)al4[e2_0 * 4 + h];
            a1_1[h] = (_Float16)al4[e1_1 * 4 + h];
            a2_1[h] = (_Float16)al4[e2_1 * 4 + h];
        }
        const int co = w * 16 + m16;
        floatx4 acc0 = {0.f, 0.f, 0.f, 0.f}, acc1 = {0.f, 0.f, 0.f, 0.f};
        #pragma unroll
        for (int kk = 0; kk < 16; ++kk) {
            const int h = kk >> 2, hf = (kk >> 1) & 1;
            const int k0 = (kk & 1) * 32 + q * 8;
            const int r1_0 = hf ? 32 + e1_0 : s1_0, r2_0 = hf ? 32 + e2_0 : s2_0;
            const int r1_1 = hf ? 32 + e1_1 : s1_1, r2_1 = hf ? 32 + e2_1 : s2_1;
            half8 b = *(const half8*)(BT + co * 512 + kk * 32 + q * 8);
            half8 x1 = *(const half8*)(R + r1_0 * RS + k0);
            half8 x2 = *(const half8*)(R + r2_0 * RS + k0);
            half8 af0 = x1 * a1_0[h] + x2 * a2_0[h];
            acc0 = __builtin_amdgcn_mfma_f32_16x16x32_f16(af0, b, acc0, 0, 0, 0);
            half8 y1 = *(const half8*)(R + r1_1 * RS + k0);
            half8 y2 = *(const half8*)(R + r2_1 * RS + k0);
            half8 af1 = y1 * a1_1[h] + y2 * a2_1[h];
            half8 vv = *(const half8*)(virt + kk * 32 + q * 8);
            af1 = (m16 == 15) ? vv : af1;
            acc1 = __builtin_amdgcn_mfma_f32_16x16x32_f16(af1, b, acc1, 0, 0, 0);
        }
        const float bv = bias[co];
        float* og = out + (size_t)g * 2048;
        #pragma unroll
        for (int r = 0; r < 4; ++r) {
            og[(q * 4 + r) * 64 + co]        = 0.25f * acc0[r] + bv;
            og[(16 + q * 4 + r) * 64 + co]   = 0.25f * acc1[r] + bv;
        }
    }

    // prefetch GEMM2 B fragments (global, independent of LDS)
    half8 b2a = *(const half8*)(BT2 + (w * 16 + m16) * 64 + 0 * 32 + q * 8);
    half8 b2b = *(const half8*)(BT2 + (w * 16 + m16) * 64 + 1 * 32 + q * 8);
    __syncthreads();   // everything in U dead; reuse as A2

    // ---- A2 rows: 0-30 temp (3-term), 31-61 0.5*eisum, 62 emean_virt, 63 zero ----
    {
        const _Float16* E = R + 32 * RS;
        for (int idx = t; idx < 62 * 32; idx += 256) {
            const int r = idx >> 5, k = (idx & 31) * 2;
            half2v v;
            if (r < 31) {
                const int ra = 2 * ((r + 30) % 31), rb = 2 * r + 1, rc = 2 * ((r + 1) % 31) + 1;
                v = *(const half2v*)(E + ra * RS + k) + *(const half2v*)(E + rb * RS + k)
                  + *(const half2v*)(E + rc * RS + k);
            } else {
                const int jj = r - 31;
                const int ra = 2 * ((jj + 30) % 31), rb = 2 * jj + 1;
                v = (*(const half2v*)(E + ra * RS + k) + *(const half2v*)(E + rb * RS + k))
                    * (_Float16)0.5f;
            }
            *(half2v*)(A2 + r * RS + k) = v;
        }
        if (t < 64) {
            float s = 0.f;
            for (int i = 0; i < 31; ++i) s += (float)E[(62 + i) * RS + t];
            A2[62 * RS + t] = (_Float16)(s * (1.f / 31.f));
        } else if (t < 128) {
            A2[63 * RS + (t - 64)] = (_Float16)0.f;
        }
    }
    __syncthreads();

    // ---- GEMM2: out2 = lrelu(A2(64x64) @ W_ec + b_ec), dedup stores ----
    {
        floatx4 z = {0.f, 0.f, 0.f, 0.f};
        floatx4 acc2[4]; acc2[0] = z; acc2[1] = z; acc2[2] = z; acc2[3] = z;
        #pragma unroll
        for (int kk = 0; kk < 2; ++kk) {
            half8 b = kk ? b2b : b2a;
            #pragma unroll
            for (int mt = 0; mt < 4; ++mt) {
                half8 a = *(const half8*)(A2 + (mt * 16 + m16) * RS + kk * 32 + q * 8);
                acc2[mt] = __builtin_amdgcn_mfma_f32_16x16x32_f16(a, b, acc2[mt], 0, 0, 0);
            }
        }
        const int co = w * 16 + m16;
        const float bv2 = bec[co];
        float* o2 = out2 + (size_t)g * 8000;   // 125*64
        #pragma unroll
        for (int mt = 0; mt < 4; ++mt) {
            #pragma unroll
            for (int r = 0; r < 4; ++r) {
                const int row = mt * 16 + q * 4 + r;
                if (row >= 63) continue;
                const float v = lrelu(acc2[mt][r] + bv2);
                if (row < 31) {
                    o2[(2 * row) * 64 + co]     = v;
                    o2[(2 * row + 1) * 64 + co] = v;
                } else if (row < 62) {
                    o2[(62 + row - 31) * 64 + co] = v;
                    o2[(94 + row - 31) * 64 + co] = v;
                } else {
                    o2[93 * 64 + co] = v;
                }
            }
        }
    }
}

extern "C" void kernel_launch(void* const* d_in, const int* in_sizes, int n_in,
                              void* d_out, int out_size, void* d_ws, size_t ws_size,
                              hipStream_t stream) {
    const float* x    = (const float*)d_in[0];
    const float* einf = (const float*)d_in[2];
    const float* W    = (const float*)d_in[5];
    const float* att  = (const float*)d_in[6];
    const float* bias = (const float*)d_in[7];
    const float* Wec  = (const float*)d_in[8];
    const float* bec  = (const float*)d_in[9];
    float* out  = (float*)d_out;
    float* out2 = out + OUT2_OFF;

    _Float16* vp  = (_Float16*)d_ws;                       // 512 halves
    _Float16* BT  = (_Float16*)((char*)d_ws + 1024);       // 64x512 halves
    _Float16* BT2 = (_Float16*)((char*)d_ws + 1024 + 65536); // 64x64 halves

    setup_prep<<<8, 256, 0, stream>>>(W, att, Wec, vp, BT, BT2);
    fused_main<<<NUM_G, 256, 0, stream>>>(x, einf, bias, bec, vp, BT, BT2, out, out2);
}